// Round 1
// baseline (2355.360 us; speedup 1.0000x reference)
//
#include <hip/hip_runtime.h>
#include <stdint.h>

#define NCLASS 32000
#define EMB    256
#define NH     512
#define BATCH  128
#define TSEQ   256
#define G4     2048   // 4*NH, gate-interleaved columns: c = 4*j + g (g: 0=f,1=i,2=c,3=o)

typedef _Float16 f16;
typedef _Float16 half8  __attribute__((ext_vector_type(8)));
typedef _Float16 half4v __attribute__((ext_vector_type(4)));
typedef float    float4v __attribute__((ext_vector_type(4)));

// ---------------- packing kernels (run every call; weights are small) ----------------

// WT[c][k] = W_gate[k][j]  (transposed + gate-interleaved, fp16), c = 4j+g, k < K
__global__ __launch_bounds__(256) void pack_wT(
    const float* __restrict__ Wf, const float* __restrict__ Wi,
    const float* __restrict__ Wc, const float* __restrict__ Wo,
    f16* __restrict__ WT, int K)
{
    int idx = blockIdx.x * 256 + threadIdx.x;          // over G4*K
    if (idx >= G4 * K) return;
    int c = idx / K, k = idx - c * K;
    int j = c >> 2, g = c & 3;
    const float* W = (g == 0) ? Wf : ((g == 1) ? Wi : ((g == 2) ? Wc : Wo));
    WT[idx] = (f16)W[k * NH + j];
}

__global__ __launch_bounds__(256) void pack_bias(
    const float* __restrict__ bf_, const float* __restrict__ bi_,
    const float* __restrict__ bc_, const float* __restrict__ bo_,
    float* __restrict__ br)
{
    int c = blockIdx.x * 256 + threadIdx.x;
    if (c >= G4) return;
    int j = c >> 2, g = c & 3;
    const float* b = (g == 0) ? bf_ : ((g == 1) ? bi_ : ((g == 2) ? bc_ : bo_));
    br[c] = b[j];
}

// fp16 copy of Whq, same [512][32000] layout
__global__ __launch_bounds__(256) void conv_whq(
    const float* __restrict__ Whq, f16* __restrict__ Wq)
{
    int i = blockIdx.x * 256 + threadIdx.x;            // over (NH*NCLASS)/4
    if (i >= (NH * NCLASS) / 4) return;
    float4v v = ((const float4v*)Whq)[i];
    half4v o; o[0] = (f16)v[0]; o[1] = (f16)v[1]; o[2] = (f16)v[2]; o[3] = (f16)v[3];
    ((half4v*)Wq)[i] = o;
}

__global__ __launch_bounds__(256) void init_hc(
    const float* __restrict__ H, const float* __restrict__ C,
    f16* __restrict__ Hh, float* __restrict__ Cw)
{
    int i = blockIdx.x * 256 + threadIdx.x;
    if (i >= BATCH * NH) return;
    Hh[i] = (f16)H[i];
    Cw[i] = C[i];
}

// ---------------- phase 1: gx[t][b][c] = (E[X[b][t]] @ WxT^T)  ----------------
// M = T*B = 32768 (r = t*128 + b), N = 2048, K = 256. 128x128 tile, BK=32, 4 waves.
__global__ __launch_bounds__(256) void gemm_gx(
    const int* __restrict__ X, const float* __restrict__ E,
    const f16* __restrict__ WxT, f16* __restrict__ gx)
{
    __shared__ union {
        struct { f16 As[128][40]; f16 Bs[128][40]; } s;
        f16 Ob[128][136];
    } sm;
    int tid  = threadIdx.x;
    int nblk = blockIdx.x & 15, mblk = blockIdx.x >> 4;
    int row0 = mblk * 128, col0 = nblk * 128;
    int wave = tid >> 6, lane = tid & 63, lrow = lane & 15, lhi = lane >> 4;
    int wr = (wave >> 1) * 64, wc = (wave & 1) * 64;

    int arow = tid >> 1, kofs = (tid & 1) * 16;
    int rg = row0 + arow;
    int b = rg & 127, t = rg >> 7;
    const float* Erow = E + (size_t)X[b * TSEQ + t] * EMB;
    const f16*   Bsrc = WxT + (size_t)(col0 + arow) * EMB + kofs;

    float4v acc[4][4];
    #pragma unroll
    for (int i = 0; i < 4; i++)
        #pragma unroll
        for (int j = 0; j < 4; j++) acc[i][j] = (float4v)0.f;

    for (int kk = 0; kk < EMB; kk += 32) {
        float4v f0 = *(const float4v*)(Erow + kk + kofs);
        float4v f1 = *(const float4v*)(Erow + kk + kofs + 4);
        float4v f2 = *(const float4v*)(Erow + kk + kofs + 8);
        float4v f3 = *(const float4v*)(Erow + kk + kofs + 12);
        half8 a0, a1;
        #pragma unroll
        for (int q = 0; q < 4; q++) {
            a0[q] = (f16)f0[q]; a0[q + 4] = (f16)f1[q];
            a1[q] = (f16)f2[q]; a1[q + 4] = (f16)f3[q];
        }
        *(half8*)&sm.s.As[arow][kofs]     = a0;
        *(half8*)&sm.s.As[arow][kofs + 8] = a1;
        *(half8*)&sm.s.Bs[arow][kofs]     = *(const half8*)(Bsrc + kk);
        *(half8*)&sm.s.Bs[arow][kofs + 8] = *(const half8*)(Bsrc + kk + 8);
        __syncthreads();
        half8 af[4], bfr[4];
        #pragma unroll
        for (int i = 0; i < 4; i++) af[i]  = *(const half8*)&sm.s.As[wr + i * 16 + lrow][lhi * 8];
        #pragma unroll
        for (int j = 0; j < 4; j++) bfr[j] = *(const half8*)&sm.s.Bs[wc + j * 16 + lrow][lhi * 8];
        #pragma unroll
        for (int i = 0; i < 4; i++)
            #pragma unroll
            for (int j = 0; j < 4; j++)
                acc[i][j] = __builtin_amdgcn_mfma_f32_16x16x32_f16(af[i], bfr[j], acc[i][j], 0, 0, 0);
        __syncthreads();
    }
    // bounce through LDS for coalesced fp16 stores
    #pragma unroll
    for (int i = 0; i < 4; i++)
        #pragma unroll
        for (int j = 0; j < 4; j++)
            #pragma unroll
            for (int r = 0; r < 4; r++)
                sm.Ob[wr + i * 16 + lhi * 4 + r][wc + j * 16 + lrow] = (f16)acc[i][j][r];
    __syncthreads();
    int orow = tid >> 1, oc0 = (tid & 1) * 64;
    f16* dst = gx + (size_t)(row0 + orow) * G4 + col0 + oc0;
    #pragma unroll
    for (int q = 0; q < 8; q++)
        *(half8*)(dst + q * 8) = *(const half8*)&sm.Ob[orow][oc0 + q * 8];
}

// ---------------- phase 2: one LSTM step ----------------
// 128 blocks; block bk owns gate columns [bk*16, bk*16+16) == hidden units [bk*4, bk*4+4).
// gates = Hin @ WhT^T (+ gx + bias), then elementwise update of C and Hout. No inter-block deps.
__global__ __launch_bounds__(256) void lstm_step(
    const f16* __restrict__ Hin, f16* __restrict__ Hout,
    float* __restrict__ C, const f16* __restrict__ WhT,
    const f16* __restrict__ gxt, const float* __restrict__ bias)
{
    __shared__ f16   Bs[16][520];
    __shared__ float Ps[128][17];
    int tid = threadIdx.x, wave = tid >> 6, lane = tid & 63;
    int lrow = lane & 15, lhi = lane >> 4;
    int col0 = blockIdx.x * 16;

    {   // stage the 16x512 fp16 weight slice once (coalesced)
        int c = tid >> 4, ko = (tid & 15) * 32;
        const f16* src = WhT + (size_t)(col0 + c) * NH + ko;
        #pragma unroll
        for (int q = 0; q < 4; q++)
            *(half8*)&Bs[c][ko + q * 8] = *(const half8*)(src + q * 8);
    }
    __syncthreads();

    // wave handles M-tiles {wave, wave+4}; single 16-wide N-tile. Barrier-free K loop.
    float4v acc0 = (float4v)0.f, acc1 = (float4v)0.f;
    const f16* Arow0 = Hin + (size_t)(wave * 16 + lrow) * NH + lhi * 8;
    const f16* Arow1 = Hin + (size_t)((wave + 4) * 16 + lrow) * NH + lhi * 8;
    const f16* Brow  = &Bs[lrow][lhi * 8];
    #pragma unroll
    for (int kk = 0; kk < NH; kk += 32) {
        half8 bfr = *(const half8*)(Brow + kk);
        half8 a0  = *(const half8*)(Arow0 + kk);
        half8 a1  = *(const half8*)(Arow1 + kk);
        acc0 = __builtin_amdgcn_mfma_f32_16x16x32_f16(a0, bfr, acc0, 0, 0, 0);
        acc1 = __builtin_amdgcn_mfma_f32_16x16x32_f16(a1, bfr, acc1, 0, 0, 0);
    }
    #pragma unroll
    for (int r = 0; r < 4; r++) {
        Ps[wave * 16 + lhi * 4 + r][lrow]       = acc0[r];
        Ps[(wave + 4) * 16 + lhi * 4 + r][lrow] = acc1[r];
    }
    __syncthreads();

    for (int it = tid; it < 512; it += 256) {       // 128 batch x 4 local hidden units
        int b = it >> 2, jl = it & 3;
        int jg = (col0 >> 2) + jl;
        const f16*   g  = gxt + (size_t)b * G4 + col0 + jl * 4;
        const float* bb = bias + col0 + jl * 4;
        float pf = Ps[b][jl * 4 + 0] + (float)g[0] + bb[0];
        float pi = Ps[b][jl * 4 + 1] + (float)g[1] + bb[1];
        float pc = Ps[b][jl * 4 + 2] + (float)g[2] + bb[2];
        float po = Ps[b][jl * 4 + 3] + (float)g[3] + bb[3];
        float F  = 1.f / (1.f + expf(-pf));
        float I  = 1.f / (1.f + expf(-pi));
        float Ct = tanhf(pc);
        float O  = 1.f / (1.f + expf(-po));
        float cOld = C[(size_t)b * NH + jg];
        float Hn   = O * tanhf(cOld);               // uses OLD C (matches reference)
        C[(size_t)b * NH + jg]    = F * cOld + I * Ct;
        Hout[(size_t)b * NH + jg] = (f16)Hn;
    }
}

// ---------------- phase 3: out = H @ Whq + bq ----------------
// M=128, N=32000, K=512. 500 blocks of 128x64, BK=32, 4 waves (each 32 rows x 64 cols).
__global__ __launch_bounds__(256) void gemm_out(
    const f16* __restrict__ Hh, const f16* __restrict__ Wq,
    const float* __restrict__ bq, float* __restrict__ out)
{
    __shared__ f16 As[128][40];
    __shared__ f16 Bs[32][80];
    int tid = threadIdx.x, wave = tid >> 6, lane = tid & 63;
    int lrow = lane & 15, lhi = lane >> 4;
    int col0 = blockIdx.x * 64;

    float4v acc[2][4];
    #pragma unroll
    for (int m = 0; m < 2; m++)
        #pragma unroll
        for (int j = 0; j < 4; j++) acc[m][j] = (float4v)0.f;

    int ar = tid >> 1, ko = (tid & 1) * 16;
    int kr = tid >> 3, co = (tid & 7) * 8;
    for (int kk = 0; kk < NH; kk += 32) {
        *(half8*)&As[ar][ko]     = *(const half8*)(Hh + (size_t)ar * NH + kk + ko);
        *(half8*)&As[ar][ko + 8] = *(const half8*)(Hh + (size_t)ar * NH + kk + ko + 8);
        *(half8*)&Bs[kr][co]     = *(const half8*)(Wq + (size_t)(kk + kr) * NCLASS + col0 + co);
        __syncthreads();
        half8 af[2];
        #pragma unroll
        for (int m = 0; m < 2; m++)
            af[m] = *(const half8*)&As[wave * 32 + m * 16 + lrow][lhi * 8];
        #pragma unroll
        for (int j = 0; j < 4; j++) {
            half8 bfr;
            #pragma unroll
            for (int i = 0; i < 8; i++) bfr[i] = Bs[lhi * 8 + i][j * 16 + lrow];
            #pragma unroll
            for (int m = 0; m < 2; m++)
                acc[m][j] = __builtin_amdgcn_mfma_f32_16x16x32_f16(af[m], bfr, acc[m][j], 0, 0, 0);
        }
        __syncthreads();
    }
    #pragma unroll
    for (int m = 0; m < 2; m++)
        #pragma unroll
        for (int j = 0; j < 4; j++) {
            int col = col0 + j * 16 + lrow;
            float bqv = bq[col];
            #pragma unroll
            for (int r = 0; r < 4; r++) {
                int row = wave * 32 + m * 16 + lhi * 4 + r;
                out[(size_t)row * NCLASS + col] = acc[m][j][r] + bqv;
            }
        }
}

// ---------------- launch ----------------
extern "C" void kernel_launch(void* const* d_in, const int* in_sizes, int n_in,
                              void* d_out, int out_size, void* d_ws, size_t ws_size,
                              hipStream_t stream)
{
    (void)in_sizes; (void)n_in; (void)out_size;
    const int*   X   = (const int*)  d_in[0];
    const float* H0  = (const float*)d_in[1];
    const float* C0  = (const float*)d_in[2];
    const float* E   = (const float*)d_in[3];
    const float* Wxf = (const float*)d_in[4];
    const float* Whf = (const float*)d_in[5];
    const float* bf_ = (const float*)d_in[6];
    const float* Wxi = (const float*)d_in[7];
    const float* Whi = (const float*)d_in[8];
    const float* bi_ = (const float*)d_in[9];
    const float* Wxc = (const float*)d_in[10];
    const float* Whc = (const float*)d_in[11];
    const float* bc_ = (const float*)d_in[12];
    const float* Wxo = (const float*)d_in[13];
    const float* Who = (const float*)d_in[14];
    const float* bo_ = (const float*)d_in[15];
    const float* Whq = (const float*)d_in[16];
    const float* bq  = (const float*)d_in[17];

    char* ws = (char*)d_ws;
    size_t o = 0;
    auto alloc = [&](size_t bytes) {
        size_t r = o;
        o = (o + bytes + 255) & ~(size_t)255;
        return r;
    };
    f16*   WxT  = (f16*)  (ws + alloc((size_t)G4 * EMB * 2));
    f16*   WhT  = (f16*)  (ws + alloc((size_t)G4 * NH * 2));
    float* bias = (float*)(ws + alloc((size_t)G4 * 4));
    f16*   Wq   = (f16*)  (ws + alloc((size_t)NH * NCLASS * 2));
    f16*   Hb0  = (f16*)  (ws + alloc((size_t)BATCH * NH * 2));
    f16*   Hb1  = (f16*)  (ws + alloc((size_t)BATCH * NH * 2));
    float* Cw   = (float*)(ws + alloc((size_t)BATCH * NH * 4));
    f16*   gx   = (f16*)  (ws + alloc((size_t)TSEQ * BATCH * G4 * 2));
    if (o > ws_size) return;   // insufficient workspace -> clean validation failure

    pack_wT  <<<(G4 * EMB + 255) / 256, 256, 0, stream>>>(Wxf, Wxi, Wxc, Wxo, WxT, EMB);
    pack_wT  <<<(G4 * NH  + 255) / 256, 256, 0, stream>>>(Whf, Whi, Whc, Who, WhT, NH);
    pack_bias<<<(G4 + 255) / 256,       256, 0, stream>>>(bf_, bi_, bc_, bo_, bias);
    conv_whq <<<(NH * NCLASS / 4 + 255) / 256, 256, 0, stream>>>(Whq, Wq);
    init_hc  <<<(BATCH * NH + 255) / 256, 256, 0, stream>>>(H0, C0, Hb0, Cw);

    gemm_gx<<<4096, 256, 0, stream>>>(X, E, WxT, gx);

    for (int t = 0; t < TSEQ; t++) {
        const f16* hin  = (t & 1) ? Hb1 : Hb0;
        f16*       hout = (t & 1) ? Hb0 : Hb1;
        lstm_step<<<128, 256, 0, stream>>>(hin, hout, Cw, WhT,
                                           gx + (size_t)t * BATCH * G4, bias);
    }
    // T=256 even -> final H is in Hb0
    gemm_out<<<NCLASS / 64, 256, 0, stream>>>(Hb0, Wq, bq, (float*)d_out);
}